// Round 1
// baseline (343.632 us; speedup 1.0000x reference)
//
#include <hip/hip_runtime.h>
#include <hip/hip_bf16.h>

// Problem constants (fixed by reference)
#define Bq 4
#define Tq 2048
#define Cq 1024
#define Hq 16
#define Dq 64
#define Mq (Bq*Tq)     // 8192 rows
#define N3q (3*Cq)     // 3072

typedef __attribute__((ext_vector_type(8))) short   short8;
typedef __attribute__((ext_vector_type(4))) float   f32x4;
typedef __attribute__((ext_vector_type(4))) unsigned short ushort4v;
typedef unsigned short u16;

__device__ __forceinline__ void gld_lds16(const u16* g, u16* l) {
  __builtin_amdgcn_global_load_lds(
      (const __attribute__((address_space(1))) unsigned int*)g,
      (__attribute__((address_space(3))) unsigned int*)l, 16, 0, 0);
}

__device__ __forceinline__ u16 f2bf(float f) {
  return __builtin_bit_cast(u16, __float2bfloat16(f));
}

__device__ __forceinline__ f32x4 mfma16(short8 a, short8 b, f32x4 c) {
  return __builtin_amdgcn_mfma_f32_16x16x32_bf16(a, b, c, 0, 0, 0);
}

// ---------------------------------------------------------------------------
// f32 -> bf16 convert (vectorized)
__global__ void cvt_bf16(const float* __restrict__ in, u16* __restrict__ out, int n) {
  int i = (blockIdx.x * 256 + threadIdx.x) * 4;
  if (i < n) {
    float4 v = *(const float4*)(in + i);
    ushort4v o;
    o.x = f2bf(v.x); o.y = f2bf(v.y); o.z = f2bf(v.z); o.w = f2bf(v.w);
    *(ushort4v*)(out + i) = o;
  }
}

// f32 [R][C] -> bf16 [C][R] tiled transpose (coalesced both sides)
__global__ void transpose_cvt(const float* __restrict__ in, u16* __restrict__ out,
                              int R, int C) {
  __shared__ float tile[32][33];
  int j0 = blockIdx.x * 32;   // col tile of input
  int i0 = blockIdx.y * 32;   // row tile of input
  int c = threadIdx.x & 31, r0 = threadIdx.x >> 5;  // 8 rows per pass
#pragma unroll
  for (int rr = 0; rr < 32; rr += 8)
    tile[r0 + rr][c] = in[(size_t)(i0 + r0 + rr) * C + j0 + c];
  __syncthreads();
#pragma unroll
  for (int rr = 0; rr < 32; rr += 8) {
    int j = r0 + rr;
    out[(size_t)(j0 + j) * R + i0 + c] = f2bf(tile[c][j]);
  }
}

// ---------------------------------------------------------------------------
// bf16 GEMM: D[M][N] = A[M][K] * Bt[N][K]^T + bias.  128x128 tile, BK=64,
// 4 waves (2x2), each wave 64x64 = 4x4 MFMA 16x16x32 tiles.
// LDS staged via global_load_lds (16B) with XOR slot swizzle:
//   element (row,k) lives at byte row*128 + ((k/8) ^ (row&7))*16 + (k%8)*2
template<int OUT_BF16>
__global__ __launch_bounds__(256, 2) void gemm_bt(
    const u16* __restrict__ A, const u16* __restrict__ Bt,
    const float* __restrict__ bias, void* __restrict__ Dp,
    int M, int N, int K)
{
  __shared__ __align__(16) u16 lA[128 * 64];
  __shared__ __align__(16) u16 lB[128 * 64];
  const int t = threadIdx.x;
  const int l = t & 63, w = t >> 6;
  const int bn = blockIdx.x, bm = blockIdx.y;
  const int wr = (w >> 1) * 64, wc = (w & 1) * 64;

  // staging: thread t handles rows (t>>3)+32c, source col pre-swizzled
  const int srow = t >> 3;
  const int scol = 8 * ((t & 7) ^ (srow & 7));
  const u16* ga = A  + (size_t)(bm * 128 + srow) * K + scol;
  const u16* gb = Bt + (size_t)(bn * 128 + srow) * K + scol;

  f32x4 acc[4][4] = {};

  for (int k0 = 0; k0 < K; k0 += 64) {
    __syncthreads();
#pragma unroll
    for (int c = 0; c < 4; ++c) {
      gld_lds16(ga + (size_t)(32 * c) * K + k0, &lA[c * 2048 + w * 512]);
      gld_lds16(gb + (size_t)(32 * c) * K + k0, &lB[c * 2048 + w * 512]);
    }
    __syncthreads();

    short8 af[4][2], bf[4][2];
#pragma unroll
    for (int m = 0; m < 4; ++m)
#pragma unroll
      for (int kk = 0; kk < 2; ++kk) {
        int ar = wr + m * 16 + (l & 15);
        int slot = (kk * 4 + (l >> 4)) ^ (l & 7);
        af[m][kk] = *(const short8*)&lA[ar * 64 + slot * 8];
        int br = wc + m * 16 + (l & 15);
        bf[m][kk] = *(const short8*)&lB[br * 64 + slot * 8];
      }
#pragma unroll
    for (int kk = 0; kk < 2; ++kk)
#pragma unroll
      for (int m = 0; m < 4; ++m)
#pragma unroll
        for (int n = 0; n < 4; ++n)
          acc[m][n] = mfma16(af[m][kk], bf[n][kk], acc[m][n]);
  }

  float bv[4];
#pragma unroll
  for (int n = 0; n < 4; ++n) bv[n] = bias[bn * 128 + wc + n * 16 + (l & 15)];
#pragma unroll
  for (int m = 0; m < 4; ++m)
#pragma unroll
    for (int r = 0; r < 4; ++r) {
      int row = bm * 128 + wr + m * 16 + (l >> 4) * 4 + r;
      size_t base = (size_t)row * N + bn * 128 + wc + (l & 15);
#pragma unroll
      for (int n = 0; n < 4; ++n) {
        float v = acc[m][n][r] + bv[n];
        if (OUT_BF16) ((u16*)Dp)[base + n * 16] = f2bf(v);
        else          ((float*)Dp)[base + n * 16] = v;
      }
    }
}

// ---------------------------------------------------------------------------
// Causal flash attention. qkv: [Mq][3072] bf16 (q|k|v each 1024 = 16 heads x 64).
// Y: [Mq][1024] bf16.  Block = 4 waves, 64 Q-rows (16/wave), KV blocks of 64.
__global__ __launch_bounds__(256, 2) void flash_attn(
    const u16* __restrict__ qkv, u16* __restrict__ Y)
{
  __shared__ __align__(16) u16 Kl[64 * 64];      // swizzled like GEMM tiles
  __shared__ __align__(16) u16 Vt[64 * 72];      // [d][key], key-block XOR swz
  __shared__ __align__(16) u16 Pl[4 * 16 * 72];  // per-wave P, padded stride 72

  const int t = threadIdx.x, l = t & 63, w = t >> 6;
  const int qb = blockIdx.x;            // 0..31
  const int bh = blockIdx.y;            // 0..63
  const int b  = bh >> 4, h = bh & 15;

  // Q fragments (A-role): rows qb*64 + w*16 + (l&15), k = kk*32 + (l>>4)*8 + i
  short8 qf[2];
  {
    const u16* qp = qkv + (size_t)(b * Tq + qb * 64 + w * 16 + (l & 15)) * N3q + h * 64;
    qf[0] = *(const short8*)(qp + ((l >> 4) * 8));
    qf[1] = *(const short8*)(qp + 32 + ((l >> 4) * 8));
  }

  float m[4], lsum[4];
  f32x4 oacc[4] = {};
#pragma unroll
  for (int r = 0; r < 4; ++r) { m[r] = -1e30f; lsum[r] = 0.f; }

  const int kcol = 8 * ((t & 7) ^ ((t >> 3) & 7));  // pre-swizzled K source col

  for (int j = 0; j <= qb; ++j) {
    __syncthreads();
    const size_t krow0 = (size_t)(b * Tq + j * 64);
    // K: 64x64 via global_load_lds, XOR slot swizzle
#pragma unroll
    for (int c = 0; c < 2; ++c)
      gld_lds16(qkv + (krow0 + c * 32 + (t >> 3)) * N3q + Cq + h * 64 + kcol,
                &Kl[c * 2048 + w * 512]);
    // V: reg-staged transpose into Vt[d][key], key-block XOR by (d>>3)
#pragma unroll
    for (int c = 0; c < 2; ++c) {
      int idx = t + 256 * c;
      int key = idx >> 3;
      int dj  = idx & 7;                 // d-block 0..7
      const u16* vp = qkv + (krow0 + key) * N3q + 2 * Cq + h * 64 + dj * 8;
      short8 v = *(const short8*)vp;
#pragma unroll
      for (int i = 0; i < 8; ++i)
        Vt[(dj * 8 + i) * 72 + (((key >> 3) ^ dj) & 7) * 8 + (key & 7)] = (u16)v[i];
    }
    __syncthreads();

    // S = Q K^T  (S[q][key]: row=(l>>4)*4+r, col=(l&15)+16n)
    f32x4 s[4] = {};
#pragma unroll
    for (int kk = 0; kk < 2; ++kk)
#pragma unroll
      for (int n = 0; n < 4; ++n) {
        int key = n * 16 + (l & 15);
        int slot = (kk * 4 + (l >> 4)) ^ (key & 7);
        short8 kf = *(const short8*)&Kl[key * 64 + slot * 8];
        s[n] = mfma16(qf[kk], kf, s[n]);
      }

    if (j == qb) {  // diagonal block: causal mask
#pragma unroll
      for (int n = 0; n < 4; ++n) {
        int key = n * 16 + (l & 15);
#pragma unroll
        for (int r = 0; r < 4; ++r) {
          int q = w * 16 + (l >> 4) * 4 + r;
          if (key > q) s[n][r] = -1e30f;
        }
      }
    }

    // online softmax (scale 1/8 folded into exp args)
#pragma unroll
    for (int r = 0; r < 4; ++r) {
      float mx = fmaxf(fmaxf(s[0][r], s[1][r]), fmaxf(s[2][r], s[3][r]));
      mx = fmaxf(mx, __shfl_xor(mx, 1));
      mx = fmaxf(mx, __shfl_xor(mx, 2));
      mx = fmaxf(mx, __shfl_xor(mx, 4));
      mx = fmaxf(mx, __shfl_xor(mx, 8));
      float mn = fmaxf(m[r], mx);
      float fac = __expf((m[r] - mn) * 0.125f);
      float rs = 0.f;
#pragma unroll
      for (int n = 0; n < 4; ++n) {
        float p = __expf((s[n][r] - mn) * 0.125f);
        s[n][r] = p;
        rs += p;
      }
      rs += __shfl_xor(rs, 1);
      rs += __shfl_xor(rs, 2);
      rs += __shfl_xor(rs, 4);
      rs += __shfl_xor(rs, 8);
      lsum[r] = lsum[r] * fac + rs;
      m[r] = mn;
#pragma unroll
      for (int dn = 0; dn < 4; ++dn) oacc[dn][r] *= fac;
    }

    // P (C-layout) -> LDS -> A-fragment layout
#pragma unroll
    for (int n = 0; n < 4; ++n)
#pragma unroll
      for (int r = 0; r < 4; ++r)
        Pl[(w * 16 + (l >> 4) * 4 + r) * 72 + n * 16 + (l & 15)] = f2bf(s[n][r]);

    // O += P V
#pragma unroll
    for (int kk = 0; kk < 2; ++kk) {
      short8 pf = *(const short8*)&Pl[(w * 16 + (l & 15)) * 72 + kk * 32 + (l >> 4) * 8];
#pragma unroll
      for (int dn = 0; dn < 4; ++dn) {
        int d = dn * 16 + (l & 15);
        int blk = (((l >> 4) + 4 * kk) ^ ((d >> 3) & 7)) & 7;
        short8 vf = *(const short8*)&Vt[d * 72 + blk * 8];
        oacc[dn] = mfma16(pf, vf, oacc[dn]);
      }
    }
  }

  // epilogue: normalize + store bf16
#pragma unroll
  for (int r = 0; r < 4; ++r) {
    float inv = 1.f / lsum[r];
    size_t row = (size_t)(b * Tq + qb * 64 + w * 16 + (l >> 4) * 4 + r);
    u16* yp = Y + row * Cq + h * 64 + (l & 15);
#pragma unroll
    for (int dn = 0; dn < 4; ++dn)
      yp[dn * 16] = f2bf(oacc[dn][r] * inv);
  }
}

// ---------------------------------------------------------------------------
extern "C" void kernel_launch(void* const* d_in, const int* in_sizes, int n_in,
                              void* d_out, int out_size, void* d_ws, size_t ws_size,
                              hipStream_t stream)
{
  const float* x      = (const float*)d_in[0];
  // d_in[1] = mask: exactly causal tril -> hardcoded, not read
  const float* W_attn = (const float*)d_in[2];
  const float* b_attn = (const float*)d_in[3];
  const float* W_proj = (const float*)d_in[4];
  const float* b_proj = (const float*)d_in[5];

  char* ws = (char*)d_ws;
  u16* x_bf    = (u16*)ws; ws += (size_t)Mq * Cq * 2;    // 16 MB
  u16* wqkv_t  = (u16*)ws; ws += (size_t)N3q * Cq * 2;   // 6 MB
  u16* wproj_t = (u16*)ws; ws += (size_t)Cq * Cq * 2;    // 2 MB
  u16* qkv     = (u16*)ws; ws += (size_t)Mq * N3q * 2;   // 48 MB
  u16* y       = (u16*)ws; ws += (size_t)Mq * Cq * 2;    // 16 MB
  if ((size_t)(ws - (char*)d_ws) > ws_size) return;      // ws too small: fail loud

  cvt_bf16<<<(Mq * Cq / 4 + 255) / 256, 256, 0, stream>>>(x, x_bf, Mq * Cq);
  transpose_cvt<<<dim3(N3q / 32, Cq / 32), 256, 0, stream>>>(W_attn, wqkv_t, Cq, N3q);
  transpose_cvt<<<dim3(Cq / 32, Cq / 32), 256, 0, stream>>>(W_proj, wproj_t, Cq, Cq);

  gemm_bt<1><<<dim3(N3q / 128, Mq / 128), 256, 0, stream>>>(
      x_bf, wqkv_t, b_attn, (void*)qkv, Mq, N3q, Cq);

  flash_attn<<<dim3(Tq / 64, Bq * Hq), 256, 0, stream>>>(qkv, y);

  gemm_bt<0><<<dim3(Cq / 128, Mq / 128), 256, 0, stream>>>(
      y, wproj_t, b_proj, d_out, Mq, Cq, Cq);
}